// Round 1
// baseline (563.713 us; speedup 1.0000x reference)
//
#include <hip/hip_runtime.h>
#include <hip/hip_bf16.h>
#include <stdint.h>

// Problem constants (head_2327872274482): B=1024, T=256, C=195, H=8
#define TT   256   // sequence length
#define CC   195   // embed dim
#define HH   8     // head dim
#define RPC  64    // rows (tokens) per staged chunk
#define NCH  4     // chunks per batch (RPC*NCH == TT)
#define XSTR 198   // shorts per xs row: 195 padded to 198 -> b32 pair reads 4B-aligned
                   // for every row; 198/2=99, 99%32=3 (odd) -> <=2-way bank aliasing (free)
#define QSTR 24    // floats per qkv row: q[0..7] k[8..15] v[16..23]; 96 B, 16B-aligned

static __device__ __forceinline__ float bf16lo(uint32_t pk) {
    return __uint_as_float(pk << 16);
}
static __device__ __forceinline__ float bf16hi(uint32_t pk) {
    return __uint_as_float(pk & 0xffff0000u);
}

__global__ __launch_bounds__(256, 2)
void fused_head(const float* __restrict__ x,
                const float* __restrict__ Wq,
                const float* __restrict__ Wk,
                const float* __restrict__ Wv,
                float* __restrict__ out)
{
    __shared__ __hip_bfloat16 xs[RPC * XSTR];   // 25,344 B
    __shared__ float qkv[TT * QSTR];            // 24,576 B  (total ~50 KB -> 3 blocks/CU)

    const int tid  = threadIdx.x;
    const int lane = tid & 63;
    // readfirstlane => compiler proves wave-uniformity => W reads become s_loads
    const int wv   = __builtin_amdgcn_readfirstlane(tid >> 6);
    const int b    = blockIdx.x;

    const float* __restrict__ xb = x + (size_t)b * (TT * CC);

    // Each wave owns outputs o = 6*wv .. 6*wv+5 (o<8:q, o<16:k, else v; h = o&7).
    const float* Wm[3] = { Wq, Wk, Wv };
    const float* Wc[6];
#pragma unroll
    for (int j = 0; j < 6; ++j) {
        const int o = wv * 6 + j;
        Wc[j] = Wm[o >> 3] + (o & 7);   // column h of the right matrix; index with c*8
    }

    for (int ch = 0; ch < NCH; ++ch) {
        // ---- stage rows [ch*64, ch*64+64) into LDS as bf16 (coalesced per-wave b32 loads)
        const int rsub = tid >> 6;  // 4 rows in flight per iteration
        for (int r4 = 0; r4 < RPC; r4 += 4) {
            const int row = r4 + rsub;
            const float* src = xb + (size_t)(ch * RPC + row) * CC;
#pragma unroll
            for (int s = 0; s < 4; ++s) {
                const int col = s * 64 + lane;
                if (col < CC)
                    xs[row * XSTR + col] = __float2bfloat16(src[col]);
            }
        }
        __syncthreads();

        // ---- projection: lane = local row; wave-uniform c loop -> scalar W loads
        {
            float acc[6] = {0.f, 0.f, 0.f, 0.f, 0.f, 0.f};
            const uint32_t* xrow =
                reinterpret_cast<const uint32_t*>(xs) + lane * (XSTR / 2);
            for (int p = 0; p < 97; ++p) {          // c = 2p, 2p+1  (0..193)
                const uint32_t pk = xrow[p];
                const float x0 = bf16lo(pk);
                const float x1 = bf16hi(pk);
#pragma unroll
                for (int j = 0; j < 6; ++j)
                    acc[j] = fmaf(x1, Wc[j][16 * p + 8],
                             fmaf(x0, Wc[j][16 * p], acc[j]));
            }
            {   // tail c = 194 (low half of word 97; high half is pad)
                const float x0 = bf16lo(xrow[97]);
#pragma unroll
                for (int j = 0; j < 6; ++j)
                    acc[j] = fmaf(x0, Wc[j][16 * 97], acc[j]);
            }
            float* dst = qkv + (ch * RPC + lane) * QSTR + wv * 6;
#pragma unroll
            for (int j = 0; j < 6; ++j) dst[j] = acc[j];
        }
        __syncthreads();   // protects both qkv writes and xs reuse next chunk
    }

    // ---- causal attention: thread t = query row; kv rows broadcast from LDS
    const int t = tid;
    const float4 q0 = *reinterpret_cast<const float4*>(qkv + t * QSTR);
    const float4 q1 = *reinterpret_cast<const float4*>(qkv + t * QSTR + 4);
    float o0 = 0.f, o1 = 0.f, o2 = 0.f, o3 = 0.f;
    float o4 = 0.f, o5 = 0.f, o6 = 0.f, o7 = 0.f;
    float denom = 0.f;
    const float SCALE = 0.07161149f;   // 1/sqrt(195)  (ref scales by embed dim)
    // scores ~ N(0, ~0.1^2): exp() without max-subtraction cannot overflow
    for (int j = 0; j <= t; ++j) {
        const float* kv = qkv + j * QSTR;
        const float4 k0 = *reinterpret_cast<const float4*>(kv + 8);
        const float4 k1 = *reinterpret_cast<const float4*>(kv + 12);
        float s = q0.x * k0.x + q0.y * k0.y + q0.z * k0.z + q0.w * k0.w
                + q1.x * k1.x + q1.y * k1.y + q1.z * k1.z + q1.w * k1.w;
        const float e = __expf(s * SCALE);
        denom += e;
        const float4 v0 = *reinterpret_cast<const float4*>(kv + 16);
        const float4 v1 = *reinterpret_cast<const float4*>(kv + 20);
        o0 = fmaf(e, v0.x, o0); o1 = fmaf(e, v0.y, o1);
        o2 = fmaf(e, v0.z, o2); o3 = fmaf(e, v0.w, o3);
        o4 = fmaf(e, v1.x, o4); o5 = fmaf(e, v1.y, o5);
        o6 = fmaf(e, v1.z, o6); o7 = fmaf(e, v1.w, o7);
    }
    const float inv = 1.0f / denom;
    float* op = out + ((size_t)b * TT + t) * HH;
    *reinterpret_cast<float4*>(op)     = make_float4(o0 * inv, o1 * inv, o2 * inv, o3 * inv);
    *reinterpret_cast<float4*>(op + 4) = make_float4(o4 * inv, o5 * inv, o6 * inv, o7 * inv);
}

extern "C" void kernel_launch(void* const* d_in, const int* in_sizes, int n_in,
                              void* d_out, int out_size, void* d_ws, size_t ws_size,
                              hipStream_t stream)
{
    const float* x  = (const float*)d_in[0];
    const float* Wq = (const float*)d_in[1];
    const float* Wk = (const float*)d_in[2];
    const float* Wv = (const float*)d_in[3];
    float* out      = (float*)d_out;
    const int B = in_sizes[0] / (TT * CC);   // = 1024
    fused_head<<<dim3(B), dim3(256), 0, stream>>>(x, Wq, Wk, Wv, out);
}

// Round 2
// 433.592 us; speedup vs baseline: 1.3001x; 1.3001x over previous
//
#include <hip/hip_runtime.h>
#include <hip/hip_bf16.h>
#include <stdint.h>

// Problem constants (head_2327872274482): B=1024, T=256, C=195, H=8
#define TT   256   // sequence length
#define CC   195   // embed dim
#define HH   8     // head dim
#define RPC  64    // rows (tokens) per staged chunk
#define NCH  4     // chunks per batch (RPC*NCH == TT)
#define XSTR 224   // shorts per xs row: covers K padded to 7*32=224 so the last
                   // A-fragment b128 read stays in-row; 448 B row stride, 16B-aligned
#define QSTR 24    // floats per qkv row: q[0..7] k[8..15] v[16..23]; 96 B, 16B-aligned
#define NKT  7     // K-tiles of 32 (7*32 = 224 >= 195)

typedef __attribute__((ext_vector_type(8))) short short8;  // bf16 MFMA A/B frag (4 VGPRs)
typedef __attribute__((ext_vector_type(4))) float f32x4;   // MFMA C/D frag

static __device__ __forceinline__ short f2bf(float v) {
    union { __hip_bfloat16 h; short s; } cv;
    cv.h = __float2bfloat16(v);
    return cv.s;
}

__global__ __launch_bounds__(256, 3)
void fused_head(const float* __restrict__ x,
                const float* __restrict__ Wq,
                const float* __restrict__ Wk,
                const float* __restrict__ Wv,
                float* __restrict__ out)
{
    __shared__ __hip_bfloat16 xs[RPC * XSTR];   // 28,672 B
    __shared__ float qkv[TT * QSTR];            // 24,576 B  (total 53.2 KB -> 3 blocks/CU)

    const int tid  = threadIdx.x;
    const int lane = tid & 63;
    const int wv   = __builtin_amdgcn_readfirstlane(tid >> 6);
    const int b    = blockIdx.x;
    const int nn   = lane & 15;     // MFMA n / m index
    const int quad = lane >> 4;     // MFMA quad

    const float* __restrict__ xb = x + (size_t)b * (TT * CC);

    // ---- B-fragment preload: W (C x 8 each) -> bf16 frags, K padded to 224, N padded to 32.
    // Layout for 16x16x32 bf16: B[k = quad*8 + j][n = lane&15], 8 elems/lane.
    // Ntile0: n=0..15 -> {Wq h, Wk h-8}; Ntile1: n=16..31 -> {Wv h-16, zero pad}.
    const float* Wsel0 = (nn < 8) ? (Wq + nn) : (Wk + nn - 8);
    const float* Wsel1 = (nn < 8) ? (Wv + nn) : nullptr;
    short8 Bf[NKT][2];
#pragma unroll
    for (int kt = 0; kt < NKT; ++kt) {
#pragma unroll
        for (int j = 0; j < 8; ++j) {
            const int k = kt * 32 + quad * 8 + j;
            float v0 = (k < CC) ? Wsel0[(size_t)k * HH] : 0.f;
            float v1 = (k < CC && Wsel1) ? Wsel1[(size_t)k * HH] : 0.f;
            Bf[kt][0][j] = f2bf(v0);
            Bf[kt][1][j] = f2bf(v1);
        }
    }

    // ---- projection: per chunk, stage 64 rows of x to LDS (bf16, zero-padded to 224),
    // then each wave MFMAs its 16-row strip: D[16 tok x 32 out] = A[16x224] * B[224x32].
    for (int ch = 0; ch < NCH; ++ch) {
        const int rsub = tid >> 6;
        for (int r4 = 0; r4 < RPC; r4 += 4) {
            const int row = r4 + rsub;
            const float* src = xb + (size_t)(ch * RPC + row) * CC;
#pragma unroll
            for (int s = 0; s < 4; ++s) {
                const int col = s * 64 + lane;
                if (col < XSTR) {                         // s==3: lanes 0..31 only
                    const float v = (col < CC) ? src[col] : 0.f;
                    xs[row * XSTR + col] = __float2bfloat16(v);
                }
            }
        }
        __syncthreads();

        f32x4 acc0 = {0.f, 0.f, 0.f, 0.f};
        f32x4 acc1 = {0.f, 0.f, 0.f, 0.f};
        const short* arow = reinterpret_cast<const short*>(xs)
                          + (wv * 16 + nn) * XSTR + quad * 8;
#pragma unroll
        for (int kt = 0; kt < NKT; ++kt) {
            const short8 a = *reinterpret_cast<const short8*>(arow + kt * 32);
            acc0 = __builtin_amdgcn_mfma_f32_16x16x32_bf16(a, Bf[kt][0], acc0, 0, 0, 0);
            acc1 = __builtin_amdgcn_mfma_f32_16x16x32_bf16(a, Bf[kt][1], acc1, 0, 0, 0);
        }
        // C/D layout: col = lane&15, row = quad*4 + reg  [m89-verified]
#pragma unroll
        for (int r = 0; r < 4; ++r) {
            const int trow = ch * RPC + wv * 16 + quad * 4 + r;
            qkv[trow * QSTR + nn] = acc0[r];              // o = n: q (n<8), k (8..15)
            if (nn < 8)
                qkv[trow * QSTR + 16 + nn] = acc1[r];     // o = 16+n: v
        }
        __syncthreads();  // protects qkv writes AND xs reuse next chunk
    }

    // ---- causal attention: thread t = query row; wave-uniform j loop, unrolled x4.
    const int t = tid;
    const float4 q0 = *reinterpret_cast<const float4*>(qkv + t * QSTR);
    const float4 q1 = *reinterpret_cast<const float4*>(qkv + t * QSTR + 4);
    float o0 = 0.f, o1 = 0.f, o2 = 0.f, o3 = 0.f;
    float o4 = 0.f, o5 = 0.f, o6 = 0.f, o7 = 0.f;
    float denom = 0.f;
    const float SCALE = 0.07161149f;   // 1/sqrt(195)  (ref scales by embed dim C)
    const int jmax = (wv + 1) * 64;    // wave-uniform trip count; mask handles j>t
    // scores ~ N(0, ~0.1^2): exp() without max-subtraction cannot overflow
    for (int j = 0; j < jmax; j += 4) {
        const float* kv = qkv + j * QSTR;
        float s[4];
#pragma unroll
        for (int u = 0; u < 4; ++u) {
            const float4 k0 = *reinterpret_cast<const float4*>(kv + u * QSTR + 8);
            const float4 k1 = *reinterpret_cast<const float4*>(kv + u * QSTR + 12);
            s[u] = q0.x * k0.x + q0.y * k0.y + q0.z * k0.z + q0.w * k0.w
                 + q1.x * k1.x + q1.y * k1.y + q1.z * k1.z + q1.w * k1.w;
        }
        float e[4];
#pragma unroll
        for (int u = 0; u < 4; ++u) {
            e[u] = (j + u <= t) ? __expf(s[u] * SCALE) : 0.f;
            denom += e[u];
        }
#pragma unroll
        for (int u = 0; u < 4; ++u) {
            const float4 v0 = *reinterpret_cast<const float4*>(kv + u * QSTR + 16);
            const float4 v1 = *reinterpret_cast<const float4*>(kv + u * QSTR + 20);
            o0 = fmaf(e[u], v0.x, o0); o1 = fmaf(e[u], v0.y, o1);
            o2 = fmaf(e[u], v0.z, o2); o3 = fmaf(e[u], v0.w, o3);
            o4 = fmaf(e[u], v1.x, o4); o5 = fmaf(e[u], v1.y, o5);
            o6 = fmaf(e[u], v1.z, o6); o7 = fmaf(e[u], v1.w, o7);
        }
    }
    const float inv = 1.0f / denom;
    float* op = out + ((size_t)b * TT + t) * HH;
    *reinterpret_cast<float4*>(op)     = make_float4(o0 * inv, o1 * inv, o2 * inv, o3 * inv);
    *reinterpret_cast<float4*>(op + 4) = make_float4(o4 * inv, o5 * inv, o6 * inv, o7 * inv);
}

extern "C" void kernel_launch(void* const* d_in, const int* in_sizes, int n_in,
                              void* d_out, int out_size, void* d_ws, size_t ws_size,
                              hipStream_t stream)
{
    const float* x  = (const float*)d_in[0];
    const float* Wq = (const float*)d_in[1];
    const float* Wk = (const float*)d_in[2];
    const float* Wv = (const float*)d_in[3];
    float* out      = (float*)d_out;
    const int B = in_sizes[0] / (TT * CC);   // = 1024
    fused_head<<<dim3(B), dim3(256), 0, stream>>>(x, Wq, Wk, Wv, out);
}

// Round 3
// 314.978 us; speedup vs baseline: 1.7897x; 1.3766x over previous
//
#include <hip/hip_runtime.h>
#include <hip/hip_bf16.h>
#include <stdint.h>

// Problem constants (head_2327872274482): B=1024, T=256, C=195, H=8
#define TT   256   // sequence length
#define CC   195   // embed dim
#define HH   8     // head dim
#define QSTR 24    // floats per qkv row: q[0..7] k[8..15] v[16..23]; 96 B, 16B-aligned
#define NKT  7     // K-tiles of 32 (7*32 = 224 >= 195)

typedef __attribute__((ext_vector_type(8))) short short8;  // bf16 MFMA A/B frag (4 VGPRs)
typedef __attribute__((ext_vector_type(4))) float f32x4;   // MFMA C/D frag

static __device__ __forceinline__ short f2bf(float v) {
    union { __hip_bfloat16 h; short s; } cv;
    cv.h = __float2bfloat16(v);
    return cv.s;
}

// LDS = qkv only: 24.5 KB -> 6 blocks/CU by LDS; VGPR capped 128 -> 4 blocks/CU.
// Grid is 1024 blocks = 4/CU -> ENTIRE grid co-resident (was 4 sequential rounds).
__global__ __launch_bounds__(256, 4)
void fused_head(const float* __restrict__ x,
                const float* __restrict__ Wq,
                const float* __restrict__ Wk,
                const float* __restrict__ Wv,
                float* __restrict__ out)
{
    __shared__ float qkv[TT * QSTR];            // 24,576 B

    const int tid  = threadIdx.x;
    const int lane = tid & 63;
    const int wv   = __builtin_amdgcn_readfirstlane(tid >> 6);
    const int b    = blockIdx.x;
    const int nn   = lane & 15;     // MFMA n / m index
    const int quad = lane >> 4;     // MFMA quad

    const float* __restrict__ xb = x + (size_t)b * (TT * CC);

    // ---- B-fragment preload: W (C x 8 each) -> bf16 frags, K padded to 224, N padded to 32.
    // Layout for 16x16x32 bf16: B[k = quad*8 + j][n = lane&15], 8 elems/lane.
    // Ntile0: n=0..15 -> {Wq h, Wk h-8}; Ntile1: n=16..31 -> {Wv h-16, zero pad}.
    const float* Wsel0 = (nn < 8) ? (Wq + nn) : (Wk + nn - 8);
    const float* Wsel1 = (nn < 8) ? (Wv + nn) : nullptr;
    short8 Bf[NKT][2];
#pragma unroll
    for (int kt = 0; kt < NKT; ++kt) {
#pragma unroll
        for (int j = 0; j < 8; ++j) {
            const int k = kt * 32 + quad * 8 + j;
            float v0 = (k < CC) ? Wsel0[(size_t)k * HH] : 0.f;
            float v1 = (k < CC && Wsel1) ? Wsel1[(size_t)k * HH] : 0.f;
            Bf[kt][0][j] = f2bf(v0);
            Bf[kt][1][j] = f2bf(v1);
        }
    }

    // ---- projection, LDS-free A-path: wave w computes 16-row strips directly from
    // global. Lane (nn,quad) reads 8 consecutive floats of row (base+nn) per K-tile
    // (scalar dwords: row stride 195 floats is only 4B-aligned), packs bf16, MFMAs.
    for (int ch = 0; ch < 4; ++ch) {
        const int rbase = ch * 64 + wv * 16;
        const float* __restrict__ xrow = xb + (size_t)(rbase + nn) * CC;

        f32x4 acc0 = {0.f, 0.f, 0.f, 0.f};
        f32x4 acc1 = {0.f, 0.f, 0.f, 0.f};
#pragma unroll
        for (int kt = 0; kt < NKT; ++kt) {
            float f[8];
#pragma unroll
            for (int j = 0; j < 8; ++j) {
                const int k = kt * 32 + quad * 8 + j;   // compile-time per (kt,j)
                f[j] = (k < CC) ? xrow[k] : 0.f;        // guard only bites at kt=6
            }
            short8 a;
#pragma unroll
            for (int j = 0; j < 8; ++j) a[j] = f2bf(f[j]);
            acc0 = __builtin_amdgcn_mfma_f32_16x16x32_bf16(a, Bf[kt][0], acc0, 0, 0, 0);
            acc1 = __builtin_amdgcn_mfma_f32_16x16x32_bf16(a, Bf[kt][1], acc1, 0, 0, 0);
        }
        // C/D layout: col = lane&15, row = quad*4 + reg  [m89-verified]
#pragma unroll
        for (int r = 0; r < 4; ++r) {
            const int trow = rbase + quad * 4 + r;
            qkv[trow * QSTR + nn] = acc0[r];              // o = n: q (n<8), k (8..15)
            if (nn < 8)
                qkv[trow * QSTR + 16 + nn] = acc1[r];     // o = 16+n: v
        }
    }
    __syncthreads();   // the ONLY barrier: proj -> attention handoff

    // ---- causal attention: thread t = query row; wave-uniform j loop, unrolled x4.
    const int t = tid;
    const float4 q0 = *reinterpret_cast<const float4*>(qkv + t * QSTR);
    const float4 q1 = *reinterpret_cast<const float4*>(qkv + t * QSTR + 4);
    float o0 = 0.f, o1 = 0.f, o2 = 0.f, o3 = 0.f;
    float o4 = 0.f, o5 = 0.f, o6 = 0.f, o7 = 0.f;
    float denom = 0.f;
    const float SCALE = 0.07161149f;   // 1/sqrt(195)  (ref scales by embed dim C)
    const int jmax = (wv + 1) * 64;    // wave-uniform trip count; mask handles j>t
    // scores ~ N(0, ~0.1^2): exp() without max-subtraction cannot overflow
    for (int j = 0; j < jmax; j += 4) {
        const float* kv = qkv + j * QSTR;
        float s[4];
#pragma unroll
        for (int u = 0; u < 4; ++u) {
            const float4 k0 = *reinterpret_cast<const float4*>(kv + u * QSTR + 8);
            const float4 k1 = *reinterpret_cast<const float4*>(kv + u * QSTR + 12);
            s[u] = q0.x * k0.x + q0.y * k0.y + q0.z * k0.z + q0.w * k0.w
                 + q1.x * k1.x + q1.y * k1.y + q1.z * k1.z + q1.w * k1.w;
        }
        float e[4];
#pragma unroll
        for (int u = 0; u < 4; ++u) {
            e[u] = (j + u <= t) ? __expf(s[u] * SCALE) : 0.f;
            denom += e[u];
        }
#pragma unroll
        for (int u = 0; u < 4; ++u) {
            const float4 v0 = *reinterpret_cast<const float4*>(kv + u * QSTR + 16);
            const float4 v1 = *reinterpret_cast<const float4*>(kv + u * QSTR + 20);
            o0 = fmaf(e[u], v0.x, o0); o1 = fmaf(e[u], v0.y, o1);
            o2 = fmaf(e[u], v0.z, o2); o3 = fmaf(e[u], v0.w, o3);
            o4 = fmaf(e[u], v1.x, o4); o5 = fmaf(e[u], v1.y, o5);
            o6 = fmaf(e[u], v1.z, o6); o7 = fmaf(e[u], v1.w, o7);
        }
    }
    const float inv = 1.0f / denom;
    float* op = out + ((size_t)b * TT + t) * HH;
    *reinterpret_cast<float4*>(op)     = make_float4(o0 * inv, o1 * inv, o2 * inv, o3 * inv);
    *reinterpret_cast<float4*>(op + 4) = make_float4(o4 * inv, o5 * inv, o6 * inv, o7 * inv);
}

extern "C" void kernel_launch(void* const* d_in, const int* in_sizes, int n_in,
                              void* d_out, int out_size, void* d_ws, size_t ws_size,
                              hipStream_t stream)
{
    const float* x  = (const float*)d_in[0];
    const float* Wq = (const float*)d_in[1];
    const float* Wk = (const float*)d_in[2];
    const float* Wv = (const float*)d_in[3];
    float* out      = (float*)d_out;
    const int B = in_sizes[0] / (TT * CC);   // = 1024
    fused_head<<<dim3(B), dim3(256), 0, stream>>>(x, Wq, Wk, Wv, out);
}

// Round 4
// 306.240 us; speedup vs baseline: 1.8408x; 1.0285x over previous
//
#include <hip/hip_runtime.h>
#include <hip/hip_bf16.h>
#include <stdint.h>

// Problem constants (head_2327872274482): B=1024, T=256, C=195, H=8
#define TT   256
#define CC   195
#define HH   8
#define NKT  7     // projection K-tiles of 32 (7*32 = 224 >= 195)
#define VSTR 260   // Vt row stride (shorts): 130 words, (2n+4q)%32 -> ~4-way max
#define PSTR 40    // P-chunk row stride (shorts): 20 words -> 2-way (free)

typedef __attribute__((ext_vector_type(8))) short short8;  // bf16 MFMA A/B frag
typedef __attribute__((ext_vector_type(4))) float f32x4;   // MFMA C/D frag

static __device__ __forceinline__ short f2bf(float v) {
    union { __hip_bfloat16 h; short s; } cv;
    cv.h = __float2bfloat16(v);
    return cv.s;
}

// LDS: Ql 4096 + Kl 4096 + Vt 8320 + Pch 5120 = 21.6 KB; VGPR<=128 -> 4 blocks/CU,
// grid 1024 = 4/CU fully co-resident.
__global__ __launch_bounds__(256, 4)
void fused_head(const float* __restrict__ x,
                const float* __restrict__ Wq,
                const float* __restrict__ Wk,
                const float* __restrict__ Wv,
                float* __restrict__ out)
{
    __shared__ short Ql[TT * 8];          // Q rows, 8 bf16 features (16 B/row)
    __shared__ short Kl[TT * 8];          // K rows, same
    __shared__ short Vt[16 * VSTR];       // V transposed: row n<8 = v_h; n=8 = 1.0; n>8 = 0
    __shared__ short Pch[4 * 16 * PSTR];  // per-wave P chunk: 16 q-rows x 32 keys (bf16)

    const int tid  = threadIdx.x;
    const int lane = tid & 63;
    const int wv   = __builtin_amdgcn_readfirstlane(tid >> 6);
    const int b    = blockIdx.x;
    const int nn   = lane & 15;
    const int quad = lane >> 4;

    // ---- init Vt rows 8..15: row 8 = ones (denom column), rows 9..15 = zeros
    {
        uint32_t* vtw = (uint32_t*)Vt;
        const int base = (8 * VSTR) / 2;   // 1040 dwords in
        for (int i = tid; i < (8 * VSTR) / 2; i += 256)
            vtw[base + i] = (i < VSTR / 2) ? 0x3F803F80u : 0u;
    }

    const float* __restrict__ xb = x + (size_t)b * (TT * CC);

    // ---- projection B-frag preload (verified layout: B[k=quad*8+j][n=lane&15])
    const float* Wsel0 = (nn < 8) ? (Wq + nn) : (Wk + nn - 8);
    const float* Wsel1 = (nn < 8) ? (Wv + nn) : nullptr;
    short8 Bf[NKT][2];
#pragma unroll
    for (int kt = 0; kt < NKT; ++kt) {
#pragma unroll
        for (int j = 0; j < 8; ++j) {
            const int k = kt * 32 + quad * 8 + j;
            float v0 = (k < CC) ? Wsel0[(size_t)k * HH] : 0.f;
            float v1 = (k < CC && Wsel1) ? Wsel1[(size_t)k * HH] : 0.f;
            Bf[kt][0][j] = f2bf(v0);
            Bf[kt][1][j] = f2bf(v1);
        }
    }

    // ---- projection: A-frags straight from global (LDS-free), MFMA, then store
    // q/k/v into attention-ready bf16 LDS layouts.
    for (int ch = 0; ch < 4; ++ch) {
        const int rbase = ch * 64 + wv * 16;
        const float* __restrict__ xrow = xb + (size_t)(rbase + nn) * CC;

        f32x4 acc0 = {0.f, 0.f, 0.f, 0.f};
        f32x4 acc1 = {0.f, 0.f, 0.f, 0.f};
#pragma unroll
        for (int kt = 0; kt < NKT; ++kt) {
            float f[8];
#pragma unroll
            for (int j = 0; j < 8; ++j) {
                const int k = kt * 32 + quad * 8 + j;
                f[j] = (k < CC) ? xrow[k] : 0.f;
            }
            short8 a;
#pragma unroll
            for (int j = 0; j < 8; ++j) a[j] = f2bf(f[j]);
            acc0 = __builtin_amdgcn_mfma_f32_16x16x32_bf16(a, Bf[kt][0], acc0, 0, 0, 0);
            acc1 = __builtin_amdgcn_mfma_f32_16x16x32_bf16(a, Bf[kt][1], acc1, 0, 0, 0);
        }
        // C/D layout: col = lane&15, row = quad*4 + reg
#pragma unroll
        for (int r = 0; r < 4; ++r) {
            const int trow = rbase + quad * 4 + r;
            const short qs = f2bf(acc0[r]);
            if (nn < 8) {
                Ql[trow * 8 + nn] = qs;                  // Q[row][feature]
                Vt[nn * VSTR + trow] = f2bf(acc1[r]);    // Vt[feature][key]
            } else {
                Kl[trow * 8 + (nn - 8)] = qs;            // K[row][feature]
            }
        }
    }
    __syncthreads();   // only barrier: proj -> attention

    // ---- MFMA attention. Wave wv owns q-tiles {wv, 7-wv, 8+wv, 15-wv}
    // (each set sums to 34 work-units -> balanced waves).
    const float SC2 = 0.07161149f * 1.44269504f;   // (1/sqrt(195)) * log2(e)
    const int qt4[4] = { wv, 7 - wv, 8 + wv, 15 - wv };
    short* Pw = Pch + wv * (16 * PSTR);

    for (int qi = 0; qi < 4; ++qi) {
        const int qt = qt4[qi];
        const int qb = qt * 16;

        short8 aQ = (short8){0, 0, 0, 0, 0, 0, 0, 0};
        if (quad == 0)
            aQ = *reinterpret_cast<const short8*>(Ql + (qb + nn) * 8);

        f32x4 accO = {0.f, 0.f, 0.f, 0.f};       // cols: 0..7 = o_h, 8 = denom
        const int nch = (qt >> 1) + 1;            // 32-key chunks covering keys<=qb+15
        for (int c = 0; c < nch; ++c) {
            const int kb = c * 32;
            // compiler barrier: keep this chunk's E-writes below last chunk's P-read
            asm volatile("" ::: "memory");
#pragma unroll
            for (int half = 0; half < 2; ++half) {
                const int kb16 = kb + half * 16;
                short8 bK = (short8){0, 0, 0, 0, 0, 0, 0, 0};
                if (quad == 0)
                    bK = *reinterpret_cast<const short8*>(Kl + (kb16 + nn) * 8);
                f32x4 s = __builtin_amdgcn_mfma_f32_16x16x32_bf16(
                              aQ, bK, (f32x4){0.f, 0.f, 0.f, 0.f}, 0, 0, 0);
                const int key = kb16 + nn;
#pragma unroll
                for (int r = 0; r < 4; ++r) {
                    const int qrow = qb + quad * 4 + r;
                    const float e = (key <= qrow) ? exp2f(s[r] * SC2) : 0.f;
                    Pw[(quad * 4 + r) * PSTR + half * 16 + nn] = f2bf(e);
                }
            }
            // all 64 lanes' E-writes must land before cross-lane A-frag read
            asm volatile("s_waitcnt lgkmcnt(0)" ::: "memory");
            const short8 aP = *reinterpret_cast<const short8*>(Pw + nn * PSTR + quad * 8);
            const short8 bV = *reinterpret_cast<const short8*>(Vt + nn * VSTR + kb + quad * 8);
            accO = __builtin_amdgcn_mfma_f32_16x16x32_bf16(aP, bV, accO, 0, 0, 0);
        }
        // epilogue: denom sits in col n=8 of the same C-layout row
#pragma unroll
        for (int r = 0; r < 4; ++r) {
            const float dn = __shfl(accO[r], (lane & 48) | 8);
            if (nn < 8) {
                const int qrow = qb + quad * 4 + r;
                out[((size_t)b * TT + qrow) * HH + nn] = accO[r] / dn;
            }
        }
    }
}

extern "C" void kernel_launch(void* const* d_in, const int* in_sizes, int n_in,
                              void* d_out, int out_size, void* d_ws, size_t ws_size,
                              hipStream_t stream)
{
    const float* x  = (const float*)d_in[0];
    const float* Wq = (const float*)d_in[1];
    const float* Wk = (const float*)d_in[2];
    const float* Wv = (const float*)d_in[3];
    float* out      = (float*)d_out;
    const int B = in_sizes[0] / (TT * CC);   // = 1024
    fused_head<<<dim3(B), dim3(256), 0, stream>>>(x, Wq, Wk, Wv, out);
}